// Round 1
// baseline (296.617 us; speedup 1.0000x reference)
//
#include <hip/hip_runtime.h>
#include <hip/hip_bf16.h>

#define NSEQ 2048
#define HID 128
#define HEADS 8
#define HD 16
#define SCALE 0.25f
#define TQ 16
#define SPLIT 16
#define KEYS_PER (NSEQ / SPLIT)   // 128 keys per block
#define KT16 (KEYS_PER / 16)      // 8 sixteen-key tiles

typedef unsigned short ushort_t;
typedef __attribute__((ext_vector_type(4))) short short4v;   // 4 bf16 (A/B frag, K=16 MFMA)
typedef __attribute__((ext_vector_type(4))) float floatx4;   // C/D frag

__device__ __forceinline__ unsigned pack_bf16x2(float a, float b) {
    __hip_bfloat16 ba = __float2bfloat16(a);
    __hip_bfloat16 bb = __float2bfloat16(b);
    return (unsigned)*(ushort_t*)&ba | ((unsigned)*(ushort_t*)&bb << 16);
}

// ---------------- kernel A: transpose 4 weight matrices into ws ----------------
__global__ void transpose_kernel(const float* __restrict__ Wq, const float* __restrict__ Wk,
                                 const float* __restrict__ Wv, const float* __restrict__ Wo,
                                 float* __restrict__ wt)
{
    int idx = blockIdx.x * 256 + threadIdx.x;     // 0..65535
    int w = idx >> 14, rem = idx & 16383;
    int row = rem >> 7, col = rem & 127;
    const float* W = (w == 0) ? Wq : (w == 1) ? Wk : (w == 2) ? Wv : Wo;
    wt[w * 16384 + col * HID + row] = W[rem];     // WT[i][j] = W[j][i]
}

// ---------------- kernel B: QKV projection ----------------
// grid 768 blocks x 128 threads; blocks [0,256)->Q (scaled bf16 hi/lo split),
// [256,512)->K bf16 rows, [512,768)->V bf16 TRANSPOSED (Vt[j][n])
__global__ __launch_bounds__(128) void qkv_kernel(
    const float* __restrict__ x, const float* __restrict__ WqT,
    const float* __restrict__ WkT, const float* __restrict__ WvT,
    const float* __restrict__ bq, const float* __restrict__ bk,
    const float* __restrict__ bv,
    __hip_bfloat16* __restrict__ Qh, __hip_bfloat16* __restrict__ Ql,
    __hip_bfloat16* __restrict__ Kb, __hip_bfloat16* __restrict__ Vt)
{
    __shared__ float xs[8 * HID];
    const int j = threadIdx.x;
    const int mat = blockIdx.x >> 8;
    const int rb = blockIdx.x & 255;
    const int r0 = rb * 8;
    const float* WT = (mat == 0) ? WqT : (mat == 1) ? WkT : WvT;
    const float* bb = (mat == 0) ? bq : (mat == 1) ? bk : bv;
    const float4* xg = (const float4*)(x + (size_t)r0 * HID);
    float4* xl = (float4*)xs;
    for (int i = j; i < 8 * HID / 4; i += 128) xl[i] = xg[i];
    __syncthreads();
    float acc[8];
#pragma unroll
    for (int r = 0; r < 8; ++r) acc[r] = 0.f;
#pragma unroll 4
    for (int i = 0; i < HID; ++i) {
        float w = WT[i * HID + j];
#pragma unroll
        for (int r = 0; r < 8; ++r) acc[r] = fmaf(xs[r * HID + i], w, acc[r]);
    }
    float bv_ = bb[j];
#pragma unroll
    for (int r = 0; r < 8; ++r) acc[r] += bv_;
    if (mat == 0) {
        // scaled hi/lo bf16 split: Qh + Ql represents acc*SCALE to ~2^-17 rel
#pragma unroll
        for (int r = 0; r < 8; ++r) {
            float qsv = acc[r] * SCALE;                 // exact (SCALE = 2^-2)
            __hip_bfloat16 hb = __float2bfloat16(qsv);
            float hf = __bfloat162float(hb);
            __hip_bfloat16 lb = __float2bfloat16(qsv - hf);
            Qh[(size_t)(r0 + r) * HID + j] = hb;
            Ql[(size_t)(r0 + r) * HID + j] = lb;
        }
    } else if (mat == 1) {
#pragma unroll
        for (int r = 0; r < 8; ++r) Kb[(size_t)(r0 + r) * HID + j] = __float2bfloat16(acc[r]);
    } else {
        // transposed store: Vt[j][r0..r0+7], 16B contiguous per thread
        unsigned u[4];
#pragma unroll
        for (int p = 0; p < 4; ++p) u[p] = pack_bf16x2(acc[2 * p], acc[2 * p + 1]);
        *(uint4*)((ushort_t*)Vt + (size_t)j * NSEQ + r0) = make_uint4(u[0], u[1], u[2], u[3]);
    }
}

// ---------------- kernel C: fused attention, all-MFMA, no LDS, no barriers ----------------
// grid 128*SPLIT blocks x 256 threads (4 independent waves; wave = 2 heads x 16 q rows)
// Trick: compute S^T = K·Q^T with mfma_16x16x16_bf16 (acc pre-loaded with bias),
// exp in-register; the S^T C-layout (lane holds P[key=4g+r][q=lane&15]) IS the
// A-fragment layout for the PV mfma over the same 16-key tile -> zero LDS traffic.
__global__ __launch_bounds__(256, 4) void attn_kernel(
    const __hip_bfloat16* __restrict__ Qh, const __hip_bfloat16* __restrict__ Ql,
    const __hip_bfloat16* __restrict__ Kb, const __hip_bfloat16* __restrict__ Vt,
    const float* __restrict__ bias, const unsigned char* __restrict__ mask,
    float* __restrict__ Op, float* __restrict__ Lp)
{
    const int t = threadIdx.x;
    const int lane = t & 63;
    const int wid = t >> 6;
    const int qi = lane & 15;          // q row (scores/A) or d col (PV out)
    const int g = lane >> 4;           // 0..3
    const int qb = blockIdx.x & 127;
    const int sp = blockIdx.x >> 7;
    const int n0 = qb * TQ;
    const int m0 = sp * KEYS_PER;
    const int h0 = wid * 2;

    // Q B-fragments (per head: hi/lo), loaded once: B[k=dim 4g+i][col=q=qi]
    short4v qhf[2], qlf[2];
#pragma unroll
    for (int hh = 0; hh < 2; ++hh) {
        const size_t qoff = (size_t)(n0 + qi) * HID + (h0 + hh) * HD + 4 * g;
        qhf[hh] = *(const short4v*)((const ushort_t*)Qh + qoff);
        qlf[hh] = *(const short4v*)((const ushort_t*)Ql + qoff);
    }

    floatx4 o[2];
    o[0] = (floatx4){0.f, 0.f, 0.f, 0.f};
    o[1] = (floatx4){0.f, 0.f, 0.f, 0.f};
    float lrun[2] = {0.f, 0.f};

    const float* bias_base = bias + (size_t)(n0 + qi) * NSEQ * HEADS;

#pragma unroll 2
    for (int kt = 0; kt < KT16; ++kt) {
        const int m1 = m0 + kt * 16;
        // mask bytes for this lane's 4 keys (m1+4g .. +3)
        const uchar4 mk = *(const uchar4*)(mask + m1 + 4 * g);
#pragma unroll
        for (int hh = 0; hh < 2; ++hh) {
            const int h = h0 + hh;
            // K A-fragment: A[row=key=qi][dim 4g+i]
            short4v ka = *(const short4v*)((const ushort_t*)Kb +
                         (size_t)(m1 + qi) * HID + h * HD + 4 * g);
            // C init = bias^T tile: lane reg r -> bias[n0+qi][m1+4g+r][h]
            const float* bp = bias_base + (size_t)(m1 + 4 * g) * HEADS + h;
            floatx4 s;
            s.x = bp[0]; s.y = bp[8]; s.z = bp[16]; s.w = bp[24];
            // S^T = (K · Qh^T + K · Ql^T) + bias   (SCALE folded into Qh/Ql)
            s = __builtin_amdgcn_mfma_f32_16x16x16bf16_1k(ka, qhf[hh], s, 0, 0, 0);
            s = __builtin_amdgcn_mfma_f32_16x16x16bf16_1k(ka, qlf[hh], s, 0, 0, 0);
            float e0 = mk.x ? 0.f : __expf(s.x);
            float e1 = mk.y ? 0.f : __expf(s.y);
            float e2 = mk.z ? 0.f : __expf(s.z);
            float e3 = mk.w ? 0.f : __expf(s.w);
            lrun[hh] += (e0 + e1) + (e2 + e3);
            // P A-fragment for PV: lane holds P[q=qi][key=4g+r] -> pack to bf16
            __hip_bfloat16 p0 = __float2bfloat16(e0);
            __hip_bfloat16 p1 = __float2bfloat16(e1);
            __hip_bfloat16 p2 = __float2bfloat16(e2);
            __hip_bfloat16 p3 = __float2bfloat16(e3);
            short4v pa = {(short)*(ushort_t*)&p0, (short)*(ushort_t*)&p1,
                          (short)*(ushort_t*)&p2, (short)*(ushort_t*)&p3};
            // V B-fragment: B[k=key 4g+i][col=d=qi] from transposed Vt
            short4v vb = *(const short4v*)((const ushort_t*)Vt +
                         (size_t)(h * HD + qi) * NSEQ + m1 + 4 * g);
            o[hh] = __builtin_amdgcn_mfma_f32_16x16x16bf16_1k(pa, vb, o[hh], 0, 0, 0);
        }
    }

    // epilogue: O partials (lane holds O[q=4g+r][d=qi]) + l partials
#pragma unroll
    for (int hh = 0; hh < 2; ++hh) {
        lrun[hh] += __shfl_xor(lrun[hh], 16);
        lrun[hh] += __shfl_xor(lrun[hh], 32);
        const int h = h0 + hh;
#pragma unroll
        for (int r = 0; r < 4; ++r)
            Op[((size_t)sp * NSEQ + n0 + 4 * g + r) * HID + h * HD + qi] = o[hh][r];
        if (g == 0)
            Lp[((size_t)sp * NSEQ + n0 + qi) * HEADS + h] = lrun[hh];
    }
}

// ---------------- kernel D: combine splits + output projection ----------------
// grid 512 blocks x 128 threads, 4 rows per block
__global__ __launch_bounds__(128) void proj_kernel(
    const float* __restrict__ Op, const float* __restrict__ Lp,
    const float* __restrict__ WoT, const float* __restrict__ bo,
    float* __restrict__ out)
{
    __shared__ float xs[4 * HID];
    const int j = threadIdx.x;
    const int r0 = blockIdx.x * 4;
    const int hh = j >> 4;
#pragma unroll
    for (int r = 0; r < 4; ++r) {
        const size_t n = r0 + r;
        float s = 0.f, l = 0.f;
#pragma unroll
        for (int sp = 0; sp < SPLIT; ++sp) {
            s += Op[((size_t)sp * NSEQ + n) * HID + j];
            l += Lp[((size_t)sp * NSEQ + n) * HEADS + hh];
        }
        xs[r * HID + j] = s / l;
    }
    __syncthreads();
    float acc[4];
#pragma unroll
    for (int r = 0; r < 4; ++r) acc[r] = 0.f;
#pragma unroll 4
    for (int i = 0; i < HID; ++i) {
        float w = WoT[i * HID + j];
#pragma unroll
        for (int r = 0; r < 4; ++r) acc[r] = fmaf(xs[r * HID + i], w, acc[r]);
    }
    float b = bo[j];
#pragma unroll
    for (int r = 0; r < 4; ++r)
        out[(size_t)(r0 + r) * HID + j] = acc[r] + b;
}

extern "C" void kernel_launch(void* const* d_in, const int* in_sizes, int n_in,
                              void* d_out, int out_size, void* d_ws, size_t ws_size,
                              hipStream_t stream) {
    const float* x    = (const float*)d_in[0];
    const float* bias = (const float*)d_in[1];
    const unsigned char* mask = (const unsigned char*)d_in[2];
    const float* Wq = (const float*)d_in[3];
    const float* bq = (const float*)d_in[4];
    const float* Wk = (const float*)d_in[5];
    const float* bk = (const float*)d_in[6];
    const float* Wv = (const float*)d_in[7];
    const float* bv = (const float*)d_in[8];
    const float* Wo = (const float*)d_in[9];
    const float* bo = (const float*)d_in[10];
    float* out = (float*)d_out;

    float* w = (float*)d_ws;
    // ws layout (float offsets):
    float* WqT = w;                                      // 16384
    float* WkT = w + 16384;
    float* WvT = w + 32768;
    float* WoT = w + 49152;
    __hip_bfloat16* Qh = (__hip_bfloat16*)(w + 65536);   // 262144 bf16
    __hip_bfloat16* Ql = (__hip_bfloat16*)(w + 196608);  // 262144 bf16
    __hip_bfloat16* Kb = (__hip_bfloat16*)(w + 327680);  // 262144 bf16 rows [n][j]
    __hip_bfloat16* Vt = (__hip_bfloat16*)(w + 458752);  // 262144 bf16 TRANSPOSED [j][n]
    float* Op  = w + 589824;                             // SPLIT*262144 fp32 (16 MB)
    float* Lp  = w + 589824 + (size_t)SPLIT * NSEQ * HID; // SPLIT*2048*8 fp32
    // total ~20.2 MB

    transpose_kernel<<<256, 256, 0, stream>>>(Wq, Wk, Wv, Wo, w);
    qkv_kernel<<<768, 128, 0, stream>>>(x, WqT, WkT, WvT, bq, bk, bv, Qh, Ql, Kb, Vt);
    attn_kernel<<<128 * SPLIT, 256, 0, stream>>>(Qh, Ql, Kb, Vt, bias, mask, Op, Lp);
    proj_kernel<<<512, 128, 0, stream>>>(Op, Lp, WoT, bo, out);
}

// Round 2
// 275.249 us; speedup vs baseline: 1.0776x; 1.0776x over previous
//
#include <hip/hip_runtime.h>
#include <hip/hip_bf16.h>

#define NSEQ 2048
#define HID 128
#define HEADS 8
#define HD 16
#define SCALE 0.25f
#define TQ 16
#define SPLIT 16
#define KEYS_PER (NSEQ / SPLIT)   // 128 keys per block
#define KT16 (KEYS_PER / 16)      // 8 sixteen-key tiles
#define NS 129                    // LDS bias tile n-stride in words (16*8 + 1 pad)

typedef unsigned short ushort_t;
typedef __attribute__((ext_vector_type(4))) short short4v;   // 4 bf16 (A/B frag, K=16 MFMA)
typedef __attribute__((ext_vector_type(4))) float floatx4;   // C/D frag
typedef __attribute__((ext_vector_type(4))) float f32x4;

__device__ __forceinline__ unsigned pack_bf16x2(float a, float b) {
    __hip_bfloat16 ba = __float2bfloat16(a);
    __hip_bfloat16 bb = __float2bfloat16(b);
    return (unsigned)*(ushort_t*)&ba | ((unsigned)*(ushort_t*)&bb << 16);
}

// ---------------- kernel A: transpose 4 weight matrices into ws ----------------
__global__ void transpose_kernel(const float* __restrict__ Wq, const float* __restrict__ Wk,
                                 const float* __restrict__ Wv, const float* __restrict__ Wo,
                                 float* __restrict__ wt)
{
    int idx = blockIdx.x * 256 + threadIdx.x;     // 0..65535
    int w = idx >> 14, rem = idx & 16383;
    int row = rem >> 7, col = rem & 127;
    const float* W = (w == 0) ? Wq : (w == 1) ? Wk : (w == 2) ? Wv : Wo;
    wt[w * 16384 + col * HID + row] = W[rem];     // WT[i][j] = W[j][i]
}

// ---------------- kernel B: QKV projection ----------------
// grid 768 blocks x 128 threads; blocks [0,256)->Q (scaled bf16 hi/lo split),
// [256,512)->K bf16 rows, [512,768)->V bf16 TRANSPOSED (Vt[j][n])
__global__ __launch_bounds__(128) void qkv_kernel(
    const float* __restrict__ x, const float* __restrict__ WqT,
    const float* __restrict__ WkT, const float* __restrict__ WvT,
    const float* __restrict__ bq, const float* __restrict__ bk,
    const float* __restrict__ bv,
    __hip_bfloat16* __restrict__ Qh, __hip_bfloat16* __restrict__ Ql,
    __hip_bfloat16* __restrict__ Kb, __hip_bfloat16* __restrict__ Vt)
{
    __shared__ float xs[8 * HID];
    const int j = threadIdx.x;
    const int mat = blockIdx.x >> 8;
    const int rb = blockIdx.x & 255;
    const int r0 = rb * 8;
    const float* WT = (mat == 0) ? WqT : (mat == 1) ? WkT : WvT;
    const float* bb = (mat == 0) ? bq : (mat == 1) ? bk : bv;
    const float4* xg = (const float4*)(x + (size_t)r0 * HID);
    float4* xl = (float4*)xs;
    for (int i = j; i < 8 * HID / 4; i += 128) xl[i] = xg[i];
    __syncthreads();
    float acc[8];
#pragma unroll
    for (int r = 0; r < 8; ++r) acc[r] = 0.f;
#pragma unroll 4
    for (int i = 0; i < HID; ++i) {
        float w = WT[i * HID + j];
#pragma unroll
        for (int r = 0; r < 8; ++r) acc[r] = fmaf(xs[r * HID + i], w, acc[r]);
    }
    float bv_ = bb[j];
#pragma unroll
    for (int r = 0; r < 8; ++r) acc[r] += bv_;
    if (mat == 0) {
        // scaled hi/lo bf16 split: Qh + Ql represents acc*SCALE to ~2^-17 rel
#pragma unroll
        for (int r = 0; r < 8; ++r) {
            float qsv = acc[r] * SCALE;                 // exact (SCALE = 2^-2)
            __hip_bfloat16 hb = __float2bfloat16(qsv);
            float hf = __bfloat162float(hb);
            __hip_bfloat16 lb = __float2bfloat16(qsv - hf);
            Qh[(size_t)(r0 + r) * HID + j] = hb;
            Ql[(size_t)(r0 + r) * HID + j] = lb;
        }
    } else if (mat == 1) {
#pragma unroll
        for (int r = 0; r < 8; ++r) Kb[(size_t)(r0 + r) * HID + j] = __float2bfloat16(acc[r]);
    } else {
        // transposed store: Vt[j][r0..r0+7], 16B contiguous per thread
        unsigned u[4];
#pragma unroll
        for (int p = 0; p < 4; ++p) u[p] = pack_bf16x2(acc[2 * p], acc[2 * p + 1]);
        *(uint4*)((ushort_t*)Vt + (size_t)j * NSEQ + r0) = make_uint4(u[0], u[1], u[2], u[3]);
    }
}

// ---------------- kernel C: fused attention, MFMA + LDS-staged bias ----------------
// grid 128*SPLIT blocks x 256 threads (4 waves; wave = 2 heads x 16 q rows).
// S^T = K·Q^T via mfma_16x16x16_bf16 with C pre-loaded from LDS-staged bias tile
// (coalesced float4 global loads, double-buffered, 1 barrier per 16-key tile).
// S^T C-layout (lane holds P[key=4g+r][q=qi]) IS the A-frag layout for PV mfma.
__global__ __launch_bounds__(256, 8) void attn_kernel(
    const __hip_bfloat16* __restrict__ Qh, const __hip_bfloat16* __restrict__ Ql,
    const __hip_bfloat16* __restrict__ Kb, const __hip_bfloat16* __restrict__ Vt,
    const float* __restrict__ bias, const unsigned char* __restrict__ mask,
    float* __restrict__ Op, float* __restrict__ Lp)
{
    __shared__ float bs[2][16 * NS];    // 16.5 KB double-buffered bias tile [n][m][h]+pad

    const int t = threadIdx.x;
    const int lane = t & 63;
    const int wid = t >> 6;
    const int qi = lane & 15;          // q row (scores/A) or d col (PV out)
    const int g = lane >> 4;           // 0..3
    const int qb = blockIdx.x & 127;
    const int sp = blockIdx.x >> 7;
    const int n0 = qb * TQ;
    const int m0 = sp * KEYS_PER;
    const int h0 = wid * 2;

    // staging role: thread (sn, sc) loads bias[n0+sn][m-tile][*] in 2 coalesced float4
    const int sn = t >> 4;             // 0..15
    const int sc = t & 15;             // 0..15
    const float* brow = bias + (size_t)(n0 + sn) * (NSEQ * HEADS)
                             + (size_t)m0 * HEADS + sc * 4;
    // LDS write addr (words): float index f = j*64 + sc*4 + e  ->  m = f>>3, h = f&7
    // addr = sn*NS + m*8 + h = sn*NS + j*64 + 4*sc
    const int wbase = sn * NS + 4 * sc;

    // Q B-fragments (per head: hi/lo), loaded once: B[k=dim 4g+i][col=q=qi]
    short4v qhf[2], qlf[2];
#pragma unroll
    for (int hh = 0; hh < 2; ++hh) {
        const size_t qoff = (size_t)(n0 + qi) * HID + (h0 + hh) * HD + 4 * g;
        qhf[hh] = *(const short4v*)((const ushort_t*)Qh + qoff);
        qlf[hh] = *(const short4v*)((const ushort_t*)Ql + qoff);
    }

    floatx4 o[2];
    o[0] = (floatx4){0.f, 0.f, 0.f, 0.f};
    o[1] = (floatx4){0.f, 0.f, 0.f, 0.f};
    float lrun[2] = {0.f, 0.f};

    // prologue: load tile 0 into regs
    f32x4 st0 = __builtin_nontemporal_load((const f32x4*)brow);
    f32x4 st1 = __builtin_nontemporal_load((const f32x4*)(brow + 64));

    for (int kt = 0; kt < KT16; ++kt) {
        float* B = &bs[kt & 1][0];
        // write staged tile to LDS (ds_write_b128 x2)
        *(f32x4*)&B[wbase] = st0;
        *(f32x4*)&B[wbase + 64] = st1;
        __syncthreads();
        // prefetch next tile into regs (in flight across this tile's compute)
        if (kt + 1 < KT16) {
            const float* bnext = brow + (size_t)(kt + 1) * 128;
            st0 = __builtin_nontemporal_load((const f32x4*)bnext);
            st1 = __builtin_nontemporal_load((const f32x4*)(bnext + 64));
        }
        const int m1 = m0 + kt * 16;
        const uchar4 mk = *(const uchar4*)(mask + m1 + 4 * g);
        const float* Brd = &B[qi * NS + 32 * g];   // bias[qi][4g+r][h] at Brd[h + 8r]
#pragma unroll
        for (int hh = 0; hh < 2; ++hh) {
            const int h = h0 + hh;
            // K A-fragment: A[row=key=qi][dim 4g+i]
            short4v ka = *(const short4v*)((const ushort_t*)Kb +
                         (size_t)(m1 + qi) * HID + h * HD + 4 * g);
            // C init = bias^T tile from LDS: reg r -> bias[n0+qi][m1+4g+r][h]
            floatx4 s;
            s.x = Brd[h];
            s.y = Brd[h + 8];
            s.z = Brd[h + 16];
            s.w = Brd[h + 24];
            // S^T = (K · Qh^T + K · Ql^T) + bias   (SCALE folded into Qh/Ql)
            s = __builtin_amdgcn_mfma_f32_16x16x16bf16_1k(ka, qhf[hh], s, 0, 0, 0);
            s = __builtin_amdgcn_mfma_f32_16x16x16bf16_1k(ka, qlf[hh], s, 0, 0, 0);
            float e0 = mk.x ? 0.f : __expf(s.x);
            float e1 = mk.y ? 0.f : __expf(s.y);
            float e2 = mk.z ? 0.f : __expf(s.z);
            float e3 = mk.w ? 0.f : __expf(s.w);
            lrun[hh] += (e0 + e1) + (e2 + e3);
            // P A-fragment for PV: lane holds P[q=qi][key=4g+r] -> pack to bf16
            __hip_bfloat16 p0 = __float2bfloat16(e0);
            __hip_bfloat16 p1 = __float2bfloat16(e1);
            __hip_bfloat16 p2 = __float2bfloat16(e2);
            __hip_bfloat16 p3 = __float2bfloat16(e3);
            short4v pa = {(short)*(ushort_t*)&p0, (short)*(ushort_t*)&p1,
                          (short)*(ushort_t*)&p2, (short)*(ushort_t*)&p3};
            // V B-fragment: B[k=key 4g+i][col=d=qi] from transposed Vt
            short4v vb = *(const short4v*)((const ushort_t*)Vt +
                         (size_t)(h * HD + qi) * NSEQ + m1 + 4 * g);
            o[hh] = __builtin_amdgcn_mfma_f32_16x16x16bf16_1k(pa, vb, o[hh], 0, 0, 0);
        }
        // no trailing barrier needed: next iter's write targets the other buffer,
        // and the next __syncthreads (lgkmcnt drain) orders reads vs the write after
    }

    // epilogue: O partials (lane holds O[q=4g+r][d=qi]) + l partials
#pragma unroll
    for (int hh = 0; hh < 2; ++hh) {
        lrun[hh] += __shfl_xor(lrun[hh], 16);
        lrun[hh] += __shfl_xor(lrun[hh], 32);
        const int h = h0 + hh;
#pragma unroll
        for (int r = 0; r < 4; ++r)
            Op[((size_t)sp * NSEQ + n0 + 4 * g + r) * HID + h * HD + qi] = o[hh][r];
        if (g == 0)
            Lp[((size_t)sp * NSEQ + n0 + qi) * HEADS + h] = lrun[hh];
    }
}

// ---------------- kernel D: combine splits + output projection ----------------
// grid 512 blocks x 128 threads, 4 rows per block
__global__ __launch_bounds__(128) void proj_kernel(
    const float* __restrict__ Op, const float* __restrict__ Lp,
    const float* __restrict__ WoT, const float* __restrict__ bo,
    float* __restrict__ out)
{
    __shared__ float xs[4 * HID];
    const int j = threadIdx.x;
    const int r0 = blockIdx.x * 4;
    const int hh = j >> 4;
#pragma unroll
    for (int r = 0; r < 4; ++r) {
        const size_t n = r0 + r;
        float s = 0.f, l = 0.f;
#pragma unroll
        for (int sp = 0; sp < SPLIT; ++sp) {
            s += Op[((size_t)sp * NSEQ + n) * HID + j];
            l += Lp[((size_t)sp * NSEQ + n) * HEADS + hh];
        }
        xs[r * HID + j] = s / l;
    }
    __syncthreads();
    float acc[4];
#pragma unroll
    for (int r = 0; r < 4; ++r) acc[r] = 0.f;
#pragma unroll 4
    for (int i = 0; i < HID; ++i) {
        float w = WoT[i * HID + j];
#pragma unroll
        for (int r = 0; r < 4; ++r) acc[r] = fmaf(xs[r * HID + i], w, acc[r]);
    }
    float b = bo[j];
#pragma unroll
    for (int r = 0; r < 4; ++r)
        out[(size_t)(r0 + r) * HID + j] = acc[r] + b;
}

extern "C" void kernel_launch(void* const* d_in, const int* in_sizes, int n_in,
                              void* d_out, int out_size, void* d_ws, size_t ws_size,
                              hipStream_t stream) {
    const float* x    = (const float*)d_in[0];
    const float* bias = (const float*)d_in[1];
    const unsigned char* mask = (const unsigned char*)d_in[2];
    const float* Wq = (const float*)d_in[3];
    const float* bq = (const float*)d_in[4];
    const float* Wk = (const float*)d_in[5];
    const float* bk = (const float*)d_in[6];
    const float* Wv = (const float*)d_in[7];
    const float* bv = (const float*)d_in[8];
    const float* Wo = (const float*)d_in[9];
    const float* bo = (const float*)d_in[10];
    float* out = (float*)d_out;

    float* w = (float*)d_ws;
    // ws layout (float offsets):
    float* WqT = w;                                      // 16384
    float* WkT = w + 16384;
    float* WvT = w + 32768;
    float* WoT = w + 49152;
    __hip_bfloat16* Qh = (__hip_bfloat16*)(w + 65536);   // 262144 bf16
    __hip_bfloat16* Ql = (__hip_bfloat16*)(w + 196608);  // 262144 bf16
    __hip_bfloat16* Kb = (__hip_bfloat16*)(w + 327680);  // 262144 bf16 rows [n][j]
    __hip_bfloat16* Vt = (__hip_bfloat16*)(w + 458752);  // 262144 bf16 TRANSPOSED [j][n]
    float* Op  = w + 589824;                             // SPLIT*262144 fp32 (16 MB)
    float* Lp  = w + 589824 + (size_t)SPLIT * NSEQ * HID; // SPLIT*2048*8 fp32
    // total ~20.2 MB

    transpose_kernel<<<256, 256, 0, stream>>>(Wq, Wk, Wv, Wo, w);
    qkv_kernel<<<768, 128, 0, stream>>>(x, WqT, WkT, WvT, bq, bk, bv, Qh, Ql, Kb, Vt);
    attn_kernel<<<128 * SPLIT, 256, 0, stream>>>(Qh, Ql, Kb, Vt, bias, mask, Op, Lp);
    proj_kernel<<<512, 128, 0, stream>>>(Op, Lp, WoT, bo, out);
}

// Round 3
// 255.658 us; speedup vs baseline: 1.1602x; 1.0766x over previous
//
#include <hip/hip_runtime.h>
#include <hip/hip_bf16.h>

#define NSEQ 2048
#define HID 128
#define HEADS 8
#define HD 16
#define SCALE 0.25f
#define TQ 16
#define SPLIT 8
#define KEYS_PER (NSEQ / SPLIT)   // 256 keys per block
#define KT16 (KEYS_PER / 16)      // 16 sixteen-key tiles
#define NS 132                    // LDS bias tile n-stride in words ([h][m] = 128 + 4 pad)

typedef unsigned short ushort_t;
typedef __attribute__((ext_vector_type(4))) short short4v;   // 4 bf16 (A/B frag, K=16 MFMA)
typedef __attribute__((ext_vector_type(4))) float floatx4;   // C/D frag
typedef __attribute__((ext_vector_type(4))) float f32x4;

__device__ __forceinline__ unsigned pack_bf16x2(float a, float b) {
    __hip_bfloat16 ba = __float2bfloat16(a);
    __hip_bfloat16 bb = __float2bfloat16(b);
    return (unsigned)*(ushort_t*)&ba | ((unsigned)*(ushort_t*)&bb << 16);
}

// ---------------- kernel A: QKV projection (W read directly, no transpose) ----------------
// grid 768 blocks x 128 threads; blocks [0,256)->Q (scaled bf16 hi/lo split),
// [256,512)->K bf16 rows, [512,768)->V bf16 TRANSPOSED (Vt[j][n]).
// out[n][j] = sum_i x[n][i]*W[j][i] + b[j]; thread j streams W row j (contiguous).
__global__ __launch_bounds__(128) void qkv_kernel(
    const float* __restrict__ x, const float* __restrict__ Wq,
    const float* __restrict__ Wk, const float* __restrict__ Wv,
    const float* __restrict__ bq, const float* __restrict__ bk,
    const float* __restrict__ bv,
    __hip_bfloat16* __restrict__ Qh, __hip_bfloat16* __restrict__ Ql,
    __hip_bfloat16* __restrict__ Kb, __hip_bfloat16* __restrict__ Vt)
{
    __shared__ float xs[8 * HID];
    const int j = threadIdx.x;
    const int mat = blockIdx.x >> 8;
    const int rb = blockIdx.x & 255;
    const int r0 = rb * 8;
    const float* W = (mat == 0) ? Wq : (mat == 1) ? Wk : Wv;
    const float* bb = (mat == 0) ? bq : (mat == 1) ? bk : bv;
    const float4* xg = (const float4*)(x + (size_t)r0 * HID);
    float4* xl = (float4*)xs;
    for (int i = j; i < 8 * HID / 4; i += 128) xl[i] = xg[i];
    __syncthreads();
    float acc[8];
#pragma unroll
    for (int r = 0; r < 8; ++r) acc[r] = 0.f;
    const float4* Wrow = (const float4*)(W + (size_t)j * HID);
#pragma unroll 4
    for (int i4 = 0; i4 < HID / 4; ++i4) {
        float4 wv = Wrow[i4];
#pragma unroll
        for (int r = 0; r < 8; ++r) {
            float4 xv = *(const float4*)&xs[r * HID + i4 * 4];
            acc[r] = fmaf(xv.x, wv.x, acc[r]);
            acc[r] = fmaf(xv.y, wv.y, acc[r]);
            acc[r] = fmaf(xv.z, wv.z, acc[r]);
            acc[r] = fmaf(xv.w, wv.w, acc[r]);
        }
    }
    float bv_ = bb[j];
#pragma unroll
    for (int r = 0; r < 8; ++r) acc[r] += bv_;
    if (mat == 0) {
        // scaled hi/lo bf16 split: Qh + Ql represents acc*SCALE to ~2^-17 rel
#pragma unroll
        for (int r = 0; r < 8; ++r) {
            float qsv = acc[r] * SCALE;                 // exact (SCALE = 2^-2)
            __hip_bfloat16 hb = __float2bfloat16(qsv);
            float hf = __bfloat162float(hb);
            __hip_bfloat16 lb = __float2bfloat16(qsv - hf);
            Qh[(size_t)(r0 + r) * HID + j] = hb;
            Ql[(size_t)(r0 + r) * HID + j] = lb;
        }
    } else if (mat == 1) {
#pragma unroll
        for (int r = 0; r < 8; ++r) Kb[(size_t)(r0 + r) * HID + j] = __float2bfloat16(acc[r]);
    } else {
        // transposed store: Vt[j][r0..r0+7], 16B contiguous per thread
        unsigned u[4];
#pragma unroll
        for (int p = 0; p < 4; ++p) u[p] = pack_bf16x2(acc[2 * p], acc[2 * p + 1]);
        *(uint4*)((ushort_t*)Vt + (size_t)j * NSEQ + r0) = make_uint4(u[0], u[1], u[2], u[3]);
    }
}

// ---------------- kernel B: fused attention, MFMA + LDS-staged bias ----------------
// grid 128*SPLIT blocks x 256 threads (4 waves; wave = 2 heads x 16 q rows).
// S^T = K·Q^T via mfma_16x16x16_bf16 with C pre-loaded from LDS-staged bias tile.
// LDS layout [n][h][m] (NS=132) -> C-init is ONE conflict-free ds_read_b128 per head.
// S^T C-layout (lane holds P[key=4g+r][q=qi]) IS the A-frag layout for PV mfma.
__global__ __launch_bounds__(256, 6) void attn_kernel(
    const __hip_bfloat16* __restrict__ Qh, const __hip_bfloat16* __restrict__ Ql,
    const __hip_bfloat16* __restrict__ Kb, const __hip_bfloat16* __restrict__ Vt,
    const float* __restrict__ bias, const unsigned char* __restrict__ mask,
    float* __restrict__ Op, float* __restrict__ Lp)
{
    __shared__ float bs[2][16 * NS];    // 16.9 KB double-buffered bias tile [n][h][m]+pad

    const int t = threadIdx.x;
    const int lane = t & 63;
    const int wid = t >> 6;
    const int qi = lane & 15;          // q row (scores/A) or d col (PV out)
    const int g = lane >> 4;           // 0..3
    const int qb = blockIdx.x & 127;
    const int sp = blockIdx.x >> 7;
    const int n0 = qb * TQ;
    const int m0 = sp * KEYS_PER;
    const int h0 = wid * 2;

    // staging role: thread (sn, sc) loads bias[n0+sn][m-tile + sc][0..7] (32B contiguous)
    const int sn = t >> 4;             // 0..15
    const int sc = t & 15;             // 0..15
    const float* brow = bias + (size_t)(n0 + sn) * (NSEQ * HEADS) + (size_t)(m0 + sc) * HEADS;
    const int wbase = sn * NS + sc;    // LDS word: + h*16

    // Q B-fragments (per head: hi/lo), loaded once: B[k=dim 4g+i][col=q=qi]
    short4v qhf[2], qlf[2];
#pragma unroll
    for (int hh = 0; hh < 2; ++hh) {
        const size_t qoff = (size_t)(n0 + qi) * HID + (h0 + hh) * HD + 4 * g;
        qhf[hh] = *(const short4v*)((const ushort_t*)Qh + qoff);
        qlf[hh] = *(const short4v*)((const ushort_t*)Ql + qoff);
    }

    floatx4 o[2];
    o[0] = (floatx4){0.f, 0.f, 0.f, 0.f};
    o[1] = (floatx4){0.f, 0.f, 0.f, 0.f};
    float lrun[2] = {0.f, 0.f};

    // prologue: load tile 0 into regs (issue-early / write-late staging)
    f32x4 st0 = __builtin_nontemporal_load((const f32x4*)brow);
    f32x4 st1 = __builtin_nontemporal_load((const f32x4*)(brow + 4));

#pragma unroll 2
    for (int kt = 0; kt < KT16; ++kt) {
        float* B = &bs[kt & 1][0];
        // scatter staged bias into [n][h][m]: 8 x ds_write_b32 (~2-way, hidden)
        B[wbase]       = st0.x; B[wbase + 16]  = st0.y;
        B[wbase + 32]  = st0.z; B[wbase + 48]  = st0.w;
        B[wbase + 64]  = st1.x; B[wbase + 80]  = st1.y;
        B[wbase + 96]  = st1.z; B[wbase + 112] = st1.w;
        __syncthreads();
        // prefetch next tile into regs (in flight across this tile's compute)
        if (kt + 1 < KT16) {
            const float* bnext = brow + (size_t)(kt + 1) * 16 * HEADS;
            st0 = __builtin_nontemporal_load((const f32x4*)bnext);
            st1 = __builtin_nontemporal_load((const f32x4*)(bnext + 4));
        }
        const int m1 = m0 + kt * 16;
        const uchar4 mk = *(const uchar4*)(mask + m1 + 4 * g);
#pragma unroll
        for (int hh = 0; hh < 2; ++hh) {
            const int h = h0 + hh;
            // K A-fragment: A[row=key=qi][dim 4g+i]
            short4v ka = *(const short4v*)((const ushort_t*)Kb +
                         (size_t)(m1 + qi) * HID + h * HD + 4 * g);
            // C init = bias^T tile from LDS: reg r -> bias[n0+qi][m1+4g+r][h]
            floatx4 s = *(const f32x4*)&B[qi * NS + h * 16 + 4 * g];
            // S^T = (K · Qh^T + K · Ql^T) + bias   (SCALE folded into Qh/Ql)
            s = __builtin_amdgcn_mfma_f32_16x16x16bf16_1k(ka, qhf[hh], s, 0, 0, 0);
            s = __builtin_amdgcn_mfma_f32_16x16x16bf16_1k(ka, qlf[hh], s, 0, 0, 0);
            float e0 = mk.x ? 0.f : __expf(s.x);
            float e1 = mk.y ? 0.f : __expf(s.y);
            float e2 = mk.z ? 0.f : __expf(s.z);
            float e3 = mk.w ? 0.f : __expf(s.w);
            lrun[hh] += (e0 + e1) + (e2 + e3);
            // P A-fragment for PV: lane holds P[q=qi][key=4g+r] -> pack to bf16
            __hip_bfloat16 p0 = __float2bfloat16(e0);
            __hip_bfloat16 p1 = __float2bfloat16(e1);
            __hip_bfloat16 p2 = __float2bfloat16(e2);
            __hip_bfloat16 p3 = __float2bfloat16(e3);
            short4v pa = {(short)*(ushort_t*)&p0, (short)*(ushort_t*)&p1,
                          (short)*(ushort_t*)&p2, (short)*(ushort_t*)&p3};
            // V B-fragment: B[k=key 4g+i][col=d=qi] from transposed Vt
            short4v vb = *(const short4v*)((const ushort_t*)Vt +
                         (size_t)(h * HD + qi) * NSEQ + m1 + 4 * g);
            o[hh] = __builtin_amdgcn_mfma_f32_16x16x16bf16_1k(pa, vb, o[hh], 0, 0, 0);
        }
        // single barrier per tile: buffers alternate; barrier kt+1 guarantees all
        // waves finished reading buffer kt&1 before it is overwritten at kt+2
    }

    // epilogue: O partials (lane holds O[q=4g+r][d=qi]) + l partials
    // Op layout [n][sp][hd], Lp layout [n][sp][h] -> contiguous combine reads in proj
#pragma unroll
    for (int hh = 0; hh < 2; ++hh) {
        lrun[hh] += __shfl_xor(lrun[hh], 16);
        lrun[hh] += __shfl_xor(lrun[hh], 32);
        const int h = h0 + hh;
#pragma unroll
        for (int r = 0; r < 4; ++r)
            Op[((size_t)(n0 + 4 * g + r) * SPLIT + sp) * HID + h * HD + qi] = o[hh][r];
        if (g == 0)
            Lp[((size_t)(n0 + qi) * SPLIT + sp) * HEADS + h] = lrun[hh];
    }
}

// ---------------- kernel C: combine splits + output projection ----------------
// grid 512 blocks x 128 threads, 4 rows per block; Wo rows read directly
__global__ __launch_bounds__(128) void proj_kernel(
    const float* __restrict__ Op, const float* __restrict__ Lp,
    const float* __restrict__ Wo, const float* __restrict__ bo,
    float* __restrict__ out)
{
    __shared__ float xs[4 * HID];
    const int j = threadIdx.x;
    const int r0 = blockIdx.x * 4;
    const int hh = j >> 4;
#pragma unroll
    for (int r = 0; r < 4; ++r) {
        const size_t n = r0 + r;
        float s = 0.f, l = 0.f;
#pragma unroll
        for (int sp = 0; sp < SPLIT; ++sp) {
            s += Op[(n * SPLIT + sp) * HID + j];
            l += Lp[(n * SPLIT + sp) * HEADS + hh];
        }
        xs[r * HID + j] = s / l;
    }
    __syncthreads();
    float acc[4];
#pragma unroll
    for (int r = 0; r < 4; ++r) acc[r] = 0.f;
    const float4* Wrow = (const float4*)(Wo + (size_t)j * HID);
#pragma unroll 4
    for (int i4 = 0; i4 < HID / 4; ++i4) {
        float4 wv = Wrow[i4];
#pragma unroll
        for (int r = 0; r < 4; ++r) {
            float4 xv = *(const float4*)&xs[r * HID + i4 * 4];
            acc[r] = fmaf(xv.x, wv.x, acc[r]);
            acc[r] = fmaf(xv.y, wv.y, acc[r]);
            acc[r] = fmaf(xv.z, wv.z, acc[r]);
            acc[r] = fmaf(xv.w, wv.w, acc[r]);
        }
    }
    float b = bo[j];
#pragma unroll
    for (int r = 0; r < 4; ++r)
        out[(size_t)(r0 + r) * HID + j] = acc[r] + b;
}

extern "C" void kernel_launch(void* const* d_in, const int* in_sizes, int n_in,
                              void* d_out, int out_size, void* d_ws, size_t ws_size,
                              hipStream_t stream) {
    const float* x    = (const float*)d_in[0];
    const float* bias = (const float*)d_in[1];
    const unsigned char* mask = (const unsigned char*)d_in[2];
    const float* Wq = (const float*)d_in[3];
    const float* bq = (const float*)d_in[4];
    const float* Wk = (const float*)d_in[5];
    const float* bk = (const float*)d_in[6];
    const float* Wv = (const float*)d_in[7];
    const float* bv = (const float*)d_in[8];
    const float* Wo = (const float*)d_in[9];
    const float* bo = (const float*)d_in[10];
    float* out = (float*)d_out;

    float* w = (float*)d_ws;
    // ws layout (float offsets):
    __hip_bfloat16* Qh = (__hip_bfloat16*)(w);           // 262144 bf16
    __hip_bfloat16* Ql = (__hip_bfloat16*)(w + 131072);  // 262144 bf16
    __hip_bfloat16* Kb = (__hip_bfloat16*)(w + 262144);  // 262144 bf16 rows [n][j]
    __hip_bfloat16* Vt = (__hip_bfloat16*)(w + 393216);  // 262144 bf16 TRANSPOSED [j][n]
    float* Op  = w + 524288;                             // NSEQ*SPLIT*HID fp32 (8 MB), [n][sp][hd]
    float* Lp  = w + 524288 + (size_t)NSEQ * SPLIT * HID; // [n][sp][h]
    // total ~11 MB

    qkv_kernel<<<768, 128, 0, stream>>>(x, Wq, Wk, Wv, bq, bk, bv, Qh, Ql, Kb, Vt);
    attn_kernel<<<128 * SPLIT, 256, 0, stream>>>(Qh, Ql, Kb, Vt, bias, mask, Op, Lp);
    proj_kernel<<<512, 128, 0, stream>>>(Op, Lp, Wo, bo, out);
}

// Round 4
// 252.797 us; speedup vs baseline: 1.1733x; 1.0113x over previous
//
#include <hip/hip_runtime.h>
#include <hip/hip_bf16.h>

#define NSEQ 2048
#define HID 128
#define HEADS 8
#define HD 16
#define SCALE 0.25f
#define SPLIT 8
#define KEYS_PER (NSEQ / SPLIT)   // 256 keys per block
#define KT (KEYS_PER / 16)        // 16 sixteen-key tiles
#define S_LDS 132                 // per-wave LDS q-row stride in words ([h][m]=128 + 4 pad)

typedef unsigned short ushort_t;
typedef __attribute__((ext_vector_type(4))) short short4v;   // 4 bf16 (A/B frag, K=16 MFMA)
typedef __attribute__((ext_vector_type(4))) float floatx4;   // C/D frag
typedef __attribute__((ext_vector_type(4))) float f32x4;

__device__ __forceinline__ unsigned pack_bf16x2(float a, float b) {
    __hip_bfloat16 ba = __float2bfloat16(a);
    __hip_bfloat16 bb = __float2bfloat16(b);
    return (unsigned)*(ushort_t*)&ba | ((unsigned)*(ushort_t*)&bb << 16);
}

// ---------------- kernel A: QKV projection ----------------
// grid 768 blocks x 128 threads; blocks [0,256)->Q (scaled bf16 hi/lo split),
// [256,512)->K bf16 rows, [512,768)->V bf16 TRANSPOSED (Vt[j][n]).
__global__ __launch_bounds__(128) void qkv_kernel(
    const float* __restrict__ x, const float* __restrict__ Wq,
    const float* __restrict__ Wk, const float* __restrict__ Wv,
    const float* __restrict__ bq, const float* __restrict__ bk,
    const float* __restrict__ bv,
    __hip_bfloat16* __restrict__ Qh, __hip_bfloat16* __restrict__ Ql,
    __hip_bfloat16* __restrict__ Kb, __hip_bfloat16* __restrict__ Vt)
{
    __shared__ float xs[8 * HID];
    const int j = threadIdx.x;
    const int mat = blockIdx.x >> 8;
    const int rb = blockIdx.x & 255;
    const int r0 = rb * 8;
    const float* W = (mat == 0) ? Wq : (mat == 1) ? Wk : Wv;
    const float* bb = (mat == 0) ? bq : (mat == 1) ? bk : bv;
    const float4* xg = (const float4*)(x + (size_t)r0 * HID);
    float4* xl = (float4*)xs;
    for (int i = j; i < 8 * HID / 4; i += 128) xl[i] = xg[i];
    __syncthreads();
    float acc[8];
#pragma unroll
    for (int r = 0; r < 8; ++r) acc[r] = 0.f;
    const float4* Wrow = (const float4*)(W + (size_t)j * HID);
#pragma unroll 4
    for (int i4 = 0; i4 < HID / 4; ++i4) {
        float4 wv = Wrow[i4];
#pragma unroll
        for (int r = 0; r < 8; ++r) {
            float4 xv = *(const float4*)&xs[r * HID + i4 * 4];
            acc[r] = fmaf(xv.x, wv.x, acc[r]);
            acc[r] = fmaf(xv.y, wv.y, acc[r]);
            acc[r] = fmaf(xv.z, wv.z, acc[r]);
            acc[r] = fmaf(xv.w, wv.w, acc[r]);
        }
    }
    float bv_ = bb[j];
#pragma unroll
    for (int r = 0; r < 8; ++r) acc[r] += bv_;
    if (mat == 0) {
        // scaled hi/lo bf16 split: Qh + Ql represents acc*SCALE to ~2^-17 rel
#pragma unroll
        for (int r = 0; r < 8; ++r) {
            float qsv = acc[r] * SCALE;                 // exact (SCALE = 2^-2)
            __hip_bfloat16 hb = __float2bfloat16(qsv);
            float hf = __bfloat162float(hb);
            __hip_bfloat16 lb = __float2bfloat16(qsv - hf);
            Qh[(size_t)(r0 + r) * HID + j] = hb;
            Ql[(size_t)(r0 + r) * HID + j] = lb;
        }
    } else if (mat == 1) {
#pragma unroll
        for (int r = 0; r < 8; ++r) Kb[(size_t)(r0 + r) * HID + j] = __float2bfloat16(acc[r]);
    } else {
        unsigned u[4];
#pragma unroll
        for (int p = 0; p < 4; ++p) u[p] = pack_bf16x2(acc[2 * p], acc[2 * p + 1]);
        *(uint4*)((ushort_t*)Vt + (size_t)j * NSEQ + r0) = make_uint4(u[0], u[1], u[2], u[3]);
    }
}

// ---------------- kernel B: fused attention, wave-independent, no barriers ----------------
// grid 256 blocks x 256 threads. Block = 64 q-rows x 256 keys; each WAVE owns 16 q-rows
// and processes ALL 8 heads -> its bias tile (16n x 16m x 8h = 8 KB) is 128 B/lane
// CONTIGUOUS: 8 fully-coalesced dwordx4 loads, transposed through wave-PRIVATE LDS
// ([q][h][m], stride 132, double-buffered). No __syncthreads; per-wave in-order DS pipe.
// S^T = K.Q^T via mfma (C preloaded with bias via one ds_read_b128 per head);
// S^T C-layout (lane holds P[key=4g+r][q=qi]) IS the A-frag layout for PV mfma.
__global__ __launch_bounds__(256, 2) void attn_kernel(
    const __hip_bfloat16* __restrict__ Qh, const __hip_bfloat16* __restrict__ Ql,
    const __hip_bfloat16* __restrict__ Kb, const __hip_bfloat16* __restrict__ Vt,
    const float* __restrict__ bias, const unsigned char* __restrict__ mask,
    float* __restrict__ Op, float* __restrict__ Lp)
{
    __shared__ float bs[4][2][16 * S_LDS];   // 66 KB: per-wave double-buffered bias tile

    const int t = threadIdx.x;
    const int lane = t & 63;
    const int wid = t >> 6;
    const int qi = lane & 15;          // q row (scores) / d col (PV out)
    const int g = lane >> 4;           // 0..3
    // staging roles: lane = sq*4 + mc; lane loads 128 contiguous bytes of row sq
    const int sq = lane >> 2;          // 0..15
    const int mc = lane & 3;           // 0..3
    const int h4 = (mc & 1) * 4;       // h-half this lane holds
    const int par = mc >> 1;           // m parity this lane holds

    const int nb = blockIdx.x & 31;
    const int sp = blockIdx.x >> 5;
    const int n0 = nb * 64 + wid * 16; // this wave's q-row base
    const int m0 = sp * KEYS_PER;

    // Q B-fragments for all 8 heads (hi/lo): B[k=dim 4g+i][col=q=qi]
    short4v qhf[8], qlf[8];
#pragma unroll
    for (int h = 0; h < 8; ++h) {
        const size_t qoff = (size_t)(n0 + qi) * HID + h * HD + 4 * g;
        qhf[h] = *(const short4v*)((const ushort_t*)Qh + qoff);
        qlf[h] = *(const short4v*)((const ushort_t*)Ql + qoff);
    }

    floatx4 o[8];
    float lrun[8];
#pragma unroll
    for (int h = 0; h < 8; ++h) {
        o[h] = (floatx4){0.f, 0.f, 0.f, 0.f};
        lrun[h] = 0.f;
    }

    // per-lane contiguous bias stream: bias[n0+sq][m0 + ...][..], 128 B per tile
    const float* bbase = bias + (size_t)(n0 + sq) * (NSEQ * HEADS)
                              + (size_t)m0 * HEADS + mc * 4;

    // prologue: tile 0 -> buffer 0
    {
        f32x4 nx[8];
#pragma unroll
        for (int p = 0; p < 8; ++p)
            nx[p] = __builtin_nontemporal_load((const f32x4*)(bbase + p * 16));
        float* B0 = &bs[wid][0][0];
#pragma unroll
        for (int p = 0; p < 8; ++p)
#pragma unroll
            for (int jj = 0; jj < 4; ++jj)
                B0[sq * S_LDS + (h4 + jj) * 16 + 2 * p + par] = nx[p][jj];
    }

#pragma unroll 2
    for (int kt = 0; kt < KT; ++kt) {
        float* B  = &bs[wid][kt & 1][0];
        float* Bn = &bs[wid][(kt + 1) & 1][0];
        const int m1 = m0 + kt * 16;
        // issue next tile's loads immediately (full tile of compute to hide latency)
        f32x4 pf[8];
        if (kt + 1 < KT) {
#pragma unroll
            for (int p = 0; p < 8; ++p)
                pf[p] = __builtin_nontemporal_load(
                            (const f32x4*)(bbase + (kt + 1) * 128 + p * 16));
        }
        const uchar4 mk = *(const uchar4*)(mask + m1 + 4 * g);
#pragma unroll
        for (int h = 0; h < 8; ++h) {
            // K A-fragment: A[row=key=qi][dim 4g+i]
            short4v ka = *(const short4v*)((const ushort_t*)Kb +
                         (size_t)(m1 + qi) * HID + h * HD + 4 * g);
            // C init: one aligned b128 -> bias[n0+qi][m1+4g..+3][h]
            floatx4 s = *(const f32x4*)&B[qi * S_LDS + h * 16 + 4 * g];
            // S^T = (K.Qh^T + K.Ql^T) + bias  (SCALE folded into Qh/Ql)
            s = __builtin_amdgcn_mfma_f32_16x16x16bf16_1k(ka, qhf[h], s, 0, 0, 0);
            s = __builtin_amdgcn_mfma_f32_16x16x16bf16_1k(ka, qlf[h], s, 0, 0, 0);
            float e0 = mk.x ? 0.f : __expf(s.x);
            float e1 = mk.y ? 0.f : __expf(s.y);
            float e2 = mk.z ? 0.f : __expf(s.z);
            float e3 = mk.w ? 0.f : __expf(s.w);
            lrun[h] += (e0 + e1) + (e2 + e3);
            __hip_bfloat16 p0 = __float2bfloat16(e0);
            __hip_bfloat16 p1 = __float2bfloat16(e1);
            __hip_bfloat16 p2 = __float2bfloat16(e2);
            __hip_bfloat16 p3 = __float2bfloat16(e3);
            short4v pa = {(short)*(ushort_t*)&p0, (short)*(ushort_t*)&p1,
                          (short)*(ushort_t*)&p2, (short)*(ushort_t*)&p3};
            // V B-fragment: B[k=key 4g+i][col=d=qi]
            short4v vb = *(const short4v*)((const ushort_t*)Vt +
                         (size_t)(h * HD + qi) * NSEQ + m1 + 4 * g);
            o[h] = __builtin_amdgcn_mfma_f32_16x16x16bf16_1k(pa, vb, o[h], 0, 0, 0);
        }
        // transpose-write next tile into the other wave-private buffer
        // (same-wave DS ops are in-order: reads of B above complete first)
        if (kt + 1 < KT) {
#pragma unroll
            for (int p = 0; p < 8; ++p)
#pragma unroll
                for (int jj = 0; jj < 4; ++jj)
                    Bn[sq * S_LDS + (h4 + jj) * 16 + 2 * p + par] = pf[p][jj];
        }
    }

    // epilogue: O partials (lane holds O[q=4g+r][d=qi]) + l partials
#pragma unroll
    for (int h = 0; h < 8; ++h) {
        lrun[h] += __shfl_xor(lrun[h], 16);
        lrun[h] += __shfl_xor(lrun[h], 32);
#pragma unroll
        for (int r = 0; r < 4; ++r)
            Op[((size_t)(n0 + 4 * g + r) * SPLIT + sp) * HID + h * HD + qi] = o[h][r];
        if (g == 0)
            Lp[((size_t)(n0 + qi) * SPLIT + sp) * HEADS + h] = lrun[h];
    }
}

// ---------------- kernel C: combine splits + output projection ----------------
// grid 512 blocks x 128 threads, 4 rows per block
__global__ __launch_bounds__(128) void proj_kernel(
    const float* __restrict__ Op, const float* __restrict__ Lp,
    const float* __restrict__ Wo, const float* __restrict__ bo,
    float* __restrict__ out)
{
    __shared__ float xs[4 * HID];
    const int j = threadIdx.x;
    const int r0 = blockIdx.x * 4;
    const int hh = j >> 4;
#pragma unroll
    for (int r = 0; r < 4; ++r) {
        const size_t n = r0 + r;
        float s = 0.f, l = 0.f;
#pragma unroll
        for (int sp = 0; sp < SPLIT; ++sp) {
            s += Op[(n * SPLIT + sp) * HID + j];
            l += Lp[(n * SPLIT + sp) * HEADS + hh];
        }
        xs[r * HID + j] = s / l;
    }
    __syncthreads();
    float acc[4];
#pragma unroll
    for (int r = 0; r < 4; ++r) acc[r] = 0.f;
    const float4* Wrow = (const float4*)(Wo + (size_t)j * HID);
#pragma unroll 4
    for (int i4 = 0; i4 < HID / 4; ++i4) {
        float4 wv = Wrow[i4];
#pragma unroll
        for (int r = 0; r < 4; ++r) {
            float4 xv = *(const float4*)&xs[r * HID + i4 * 4];
            acc[r] = fmaf(xv.x, wv.x, acc[r]);
            acc[r] = fmaf(xv.y, wv.y, acc[r]);
            acc[r] = fmaf(xv.z, wv.z, acc[r]);
            acc[r] = fmaf(xv.w, wv.w, acc[r]);
        }
    }
    float b = bo[j];
#pragma unroll
    for (int r = 0; r < 4; ++r)
        out[(size_t)(r0 + r) * HID + j] = acc[r] + b;
}

extern "C" void kernel_launch(void* const* d_in, const int* in_sizes, int n_in,
                              void* d_out, int out_size, void* d_ws, size_t ws_size,
                              hipStream_t stream) {
    const float* x    = (const float*)d_in[0];
    const float* bias = (const float*)d_in[1];
    const unsigned char* mask = (const unsigned char*)d_in[2];
    const float* Wq = (const float*)d_in[3];
    const float* bq = (const float*)d_in[4];
    const float* Wk = (const float*)d_in[5];
    const float* bk = (const float*)d_in[6];
    const float* Wv = (const float*)d_in[7];
    const float* bv = (const float*)d_in[8];
    const float* Wo = (const float*)d_in[9];
    const float* bo = (const float*)d_in[10];
    float* out = (float*)d_out;

    float* w = (float*)d_ws;
    // ws layout (float offsets):
    __hip_bfloat16* Qh = (__hip_bfloat16*)(w);           // 262144 bf16
    __hip_bfloat16* Ql = (__hip_bfloat16*)(w + 131072);  // 262144 bf16
    __hip_bfloat16* Kb = (__hip_bfloat16*)(w + 262144);  // 262144 bf16 rows [n][j]
    __hip_bfloat16* Vt = (__hip_bfloat16*)(w + 393216);  // 262144 bf16 TRANSPOSED [j][n]
    float* Op  = w + 524288;                             // NSEQ*SPLIT*HID fp32 (8 MB), [n][sp][hd]
    float* Lp  = w + 524288 + (size_t)NSEQ * SPLIT * HID; // [n][sp][h]
    // total ~11 MB

    qkv_kernel<<<768, 128, 0, stream>>>(x, Wq, Wk, Wv, bq, bk, bv, Qh, Ql, Kb, Vt);
    attn_kernel<<<32 * SPLIT, 256, 0, stream>>>(Qh, Ql, Kb, Vt, bias, mask, Op, Lp);
    proj_kernel<<<512, 128, 0, stream>>>(Op, Lp, Wo, bo, out);
}